// Round 1
// baseline (1285.694 us; speedup 1.0000x reference)
//
#include <hip/hip_runtime.h>
#include <hip/hip_bf16.h>
#include <math.h>

#define HIDDEN 2048
#define INTER 1024
#define NEXP 64
#define TOPK 8
#define NTOK 512

// ---------------- Router + top-8 + softmax ----------------
// one block (64 threads = 1 wave) per token; lane e owns expert e's logit
__global__ void router_topk_kernel(const float* __restrict__ x,
                                   const float* __restrict__ wr,
                                   int* __restrict__ topk_idx,
                                   float* __restrict__ gates) {
    const int t = blockIdx.x;
    const int lane = threadIdx.x;
    __shared__ float sx[HIDDEN];
    for (int i = lane; i < HIDDEN / 4; i += 64)
        *(float4*)&sx[i * 4] = *(const float4*)(x + (size_t)t * HIDDEN + i * 4);
    __syncthreads();

    float acc = 0.f;
#pragma unroll 8
    for (int d = 0; d < HIDDEN; ++d)
        acc = fmaf(sx[d], wr[d * NEXP + lane], acc);

    // iterative top-8 with low-index tie-break (matches jax.lax.top_k)
    float cur = acc;
    float topv[TOPK];
    int topi[TOPK];
#pragma unroll
    for (int k = 0; k < TOPK; ++k) {
        float bv = cur;
        int bi = lane;
#pragma unroll
        for (int off = 32; off > 0; off >>= 1) {
            float ov = __shfl_xor(bv, off, 64);
            int oi = __shfl_xor(bi, off, 64);
            if (ov > bv || (ov == bv && oi < bi)) { bv = ov; bi = oi; }
        }
        topv[k] = bv;
        topi[k] = bi;
        if (lane == bi) cur = -INFINITY;
    }
    if (lane == 0) {
        float m = topv[0];
        float ex[TOPK], s = 0.f;
#pragma unroll
        for (int k = 0; k < TOPK; ++k) { ex[k] = __expf(topv[k] - m); s += ex[k]; }
        float inv = 1.f / s;
#pragma unroll
        for (int k = 0; k < TOPK; ++k) {
            gates[t * TOPK + k] = ex[k] * inv;
            topk_idx[t * TOPK + k] = topi[k];
        }
    }
}

// ---------------- Deterministic bucket build ----------------
// one block per expert; prefix-scan over 512 tokens (2 per thread)
__global__ void build_buckets_kernel(const int* __restrict__ topk_idx,
                                     const float* __restrict__ gates,
                                     int* __restrict__ bucket_tok,
                                     float* __restrict__ bucket_gate,
                                     int* __restrict__ count) {
    const int e = blockIdx.x;
    const int tid = threadIdx.x;
    __shared__ int scan[256];
    const int t0 = tid * 2;
    int f0 = 0, f1 = 0;
    float g0 = 0.f, g1 = 0.f;
#pragma unroll
    for (int k = 0; k < TOPK; ++k) {
        if (topk_idx[t0 * TOPK + k] == e) { f0 = 1; g0 = gates[t0 * TOPK + k]; }
        if (topk_idx[(t0 + 1) * TOPK + k] == e) { f1 = 1; g1 = gates[(t0 + 1) * TOPK + k]; }
    }
    int s = f0 + f1;
    scan[tid] = s;
    __syncthreads();
    for (int off = 1; off < 256; off <<= 1) {
        int add = (tid >= off) ? scan[tid - off] : 0;
        __syncthreads();
        scan[tid] += add;
        __syncthreads();
    }
    int excl = scan[tid] - s;
    if (f0) { bucket_tok[e * NTOK + excl] = t0; bucket_gate[e * NTOK + excl] = g0; }
    if (f1) { bucket_tok[e * NTOK + excl + f0] = t0 + 1; bucket_gate[e * NTOK + excl + f0] = g1; }
    if (tid == 255) count[e] = scan[255];
}

__global__ void base_scan_kernel(const int* __restrict__ count, int* __restrict__ base) {
    if (threadIdx.x == 0) {
        int acc = 0;
        for (int e = 0; e < NEXP; ++e) { base[e] = acc; acc += count[e]; }
    }
}

// ---------------- Fused gate/up + SiLU ----------------
// grid: 64 experts x 16 inter-chunks (64 wide). block 256 (16x16 threads).
// Each thread computes a 4-token x 4-inter block of H and U.
#define KT 16
#define TT 64
#define CI 64

__global__ __launch_bounds__(256) void gateup_kernel(
    const float* __restrict__ x, const float* __restrict__ wg,
    const float* __restrict__ wu, const int* __restrict__ bucket_tok,
    const float* __restrict__ bucket_gate, const int* __restrict__ count,
    const int* __restrict__ base, float* __restrict__ A) {
    const int e = blockIdx.x >> 4;
    const int c0 = (blockIdx.x & 15) * CI;
    const int n = count[e];
    if (n == 0) return;
    const int b0 = base[e];

    __shared__ float sx[KT][TT];
    __shared__ float swg[KT][CI];
    __shared__ float swu[KT][CI];
    __shared__ int stok[TT];
    __shared__ float sgate[TT];

    const int tid = threadIdx.x;
    const int tx = tid & 15, ty = tid >> 4;
    const float* wge = wg + (size_t)e * HIDDEN * INTER;
    const float* wue = wu + (size_t)e * HIDDEN * INTER;

    for (int t0 = 0; t0 < n; t0 += TT) {
        if (tid < TT) {
            int p = t0 + tid;
            stok[tid] = (p < n) ? bucket_tok[e * NTOK + p] : 0;
            sgate[tid] = (p < n) ? bucket_gate[e * NTOK + p] : 0.f;
        }
        __syncthreads();
        float hacc[4][4] = {{0}}, uacc[4][4] = {{0}};

        for (int kk = 0; kk < HIDDEN; kk += KT) {
            {   // stage X transposed: wave j loads k-range [j*4, j*4+4) for token l
                int l = tid & 63, j = tid >> 6;
                const float4 xv = *(const float4*)(x + (size_t)stok[l] * HIDDEN + kk + j * 4);
                sx[j * 4 + 0][l] = xv.x; sx[j * 4 + 1][l] = xv.y;
                sx[j * 4 + 2][l] = xv.z; sx[j * 4 + 3][l] = xv.w;
            }
            {   // stage weights: thread -> row r, col-group cg
                int r = tid >> 4, cg = (tid & 15) * 4;
                *(float4*)&swg[r][cg] = *(const float4*)(wge + (size_t)(kk + r) * INTER + c0 + cg);
                *(float4*)&swu[r][cg] = *(const float4*)(wue + (size_t)(kk + r) * INTER + c0 + cg);
            }
            __syncthreads();
#pragma unroll
            for (int k = 0; k < KT; ++k) {
                const float4 xa = *(const float4*)&sx[k][ty * 4];
                const float4 ga = *(const float4*)&swg[k][tx * 4];
                const float4 ua = *(const float4*)&swu[k][tx * 4];
                const float xs[4] = {xa.x, xa.y, xa.z, xa.w};
                const float gs[4] = {ga.x, ga.y, ga.z, ga.w};
                const float us[4] = {ua.x, ua.y, ua.z, ua.w};
#pragma unroll
                for (int a = 0; a < 4; ++a)
#pragma unroll
                    for (int b = 0; b < 4; ++b) {
                        hacc[a][b] = fmaf(xs[a], gs[b], hacc[a][b]);
                        uacc[a][b] = fmaf(xs[a], us[b], uacc[a][b]);
                    }
            }
            __syncthreads();
        }
        // epilogue: A = silu(h) * u * gate
#pragma unroll
        for (int a = 0; a < 4; ++a) {
            int p = t0 + ty * 4 + a;
            if (p < n) {
                float gt = sgate[ty * 4 + a];
                float4 av;
                float h0 = hacc[a][0], h1 = hacc[a][1], h2 = hacc[a][2], h3 = hacc[a][3];
                av.x = h0 / (1.f + __expf(-h0)) * uacc[a][0] * gt;
                av.y = h1 / (1.f + __expf(-h1)) * uacc[a][1] * gt;
                av.z = h2 / (1.f + __expf(-h2)) * uacc[a][2] * gt;
                av.w = h3 / (1.f + __expf(-h3)) * uacc[a][3] * gt;
                *(float4*)(A + (size_t)(b0 + p) * INTER + c0 + tx * 4) = av;
            }
        }
        __syncthreads();
    }
}

// ---------------- Down projection + scatter-add ----------------
// grid: 64 experts x 32 out-chunks (64 wide). block 256 (16x16).
__global__ __launch_bounds__(256) void down_kernel(
    const float* __restrict__ A, const float* __restrict__ wd,
    const int* __restrict__ bucket_tok, const int* __restrict__ count,
    const int* __restrict__ base, float* __restrict__ out) {
    const int e = blockIdx.x >> 5;
    const int c0 = (blockIdx.x & 31) * CI;
    const int n = count[e];
    if (n == 0) return;
    const int b0 = base[e];

    __shared__ float sa[KT][TT];
    __shared__ float swd[KT][CI];
    __shared__ int stok[TT];

    const int tid = threadIdx.x;
    const int tx = tid & 15, ty = tid >> 4;
    const float* wde = wd + (size_t)e * INTER * HIDDEN;

    for (int t0 = 0; t0 < n; t0 += TT) {
        if (tid < TT) {
            int p = t0 + tid;
            stok[tid] = (p < n) ? bucket_tok[e * NTOK + p] : 0;
        }
        __syncthreads();
        float acc[4][4] = {{0}};

        for (int kk = 0; kk < INTER; kk += KT) {
            {
                int l = tid & 63, j = tid >> 6;
                int p = t0 + l;
                int row = b0 + ((p < n) ? p : 0);
                const float4 av = *(const float4*)(A + (size_t)row * INTER + kk + j * 4);
                sa[j * 4 + 0][l] = av.x; sa[j * 4 + 1][l] = av.y;
                sa[j * 4 + 2][l] = av.z; sa[j * 4 + 3][l] = av.w;
            }
            {
                int r = tid >> 4, cg = (tid & 15) * 4;
                *(float4*)&swd[r][cg] = *(const float4*)(wde + (size_t)(kk + r) * HIDDEN + c0 + cg);
            }
            __syncthreads();
#pragma unroll
            for (int k = 0; k < KT; ++k) {
                const float4 aa = *(const float4*)&sa[k][ty * 4];
                const float4 wa = *(const float4*)&swd[k][tx * 4];
                const float as[4] = {aa.x, aa.y, aa.z, aa.w};
                const float ws[4] = {wa.x, wa.y, wa.z, wa.w};
#pragma unroll
                for (int a = 0; a < 4; ++a)
#pragma unroll
                    for (int b = 0; b < 4; ++b)
                        acc[a][b] = fmaf(as[a], ws[b], acc[a][b]);
            }
            __syncthreads();
        }
#pragma unroll
        for (int a = 0; a < 4; ++a) {
            int p = t0 + ty * 4 + a;
            if (p < n) {
                int tok = stok[ty * 4 + a];
                float* o = out + (size_t)tok * HIDDEN + c0 + tx * 4;
                unsafeAtomicAdd(o + 0, acc[a][0]);
                unsafeAtomicAdd(o + 1, acc[a][1]);
                unsafeAtomicAdd(o + 2, acc[a][2]);
                unsafeAtomicAdd(o + 3, acc[a][3]);
            }
        }
        __syncthreads();
    }
}

extern "C" void kernel_launch(void* const* d_in, const int* in_sizes, int n_in,
                              void* d_out, int out_size, void* d_ws, size_t ws_size,
                              hipStream_t stream) {
    const float* x = (const float*)d_in[0];
    const float* wr = (const float*)d_in[1];
    const float* wg = (const float*)d_in[2];
    const float* wu = (const float*)d_in[3];
    const float* wd = (const float*)d_in[4];
    float* out = (float*)d_out;

    // workspace layout
    char* ws = (char*)d_ws;
    size_t off = 0;
    auto alloc = [&](size_t bytes) {
        void* p = ws + off;
        off = (off + bytes + 255) & ~(size_t)255;
        return p;
    };
    int* topk_idx = (int*)alloc(NTOK * TOPK * sizeof(int));
    float* gates = (float*)alloc(NTOK * TOPK * sizeof(float));
    int* bucket_tok = (int*)alloc(NEXP * NTOK * sizeof(int));
    float* bucket_gate = (float*)alloc(NEXP * NTOK * sizeof(float));
    int* count = (int*)alloc(NEXP * sizeof(int));
    int* base = (int*)alloc(NEXP * sizeof(int));
    float* A = (float*)alloc((size_t)NTOK * TOPK * INTER * sizeof(float));
    (void)ws_size;

    hipMemsetAsync(d_out, 0, (size_t)NTOK * HIDDEN * sizeof(float), stream);

    router_topk_kernel<<<NTOK, 64, 0, stream>>>(x, wr, topk_idx, gates);
    build_buckets_kernel<<<NEXP, 256, 0, stream>>>(topk_idx, gates, bucket_tok, bucket_gate, count);
    base_scan_kernel<<<1, 64, 0, stream>>>(count, base);
    gateup_kernel<<<NEXP * 16, 256, 0, stream>>>(x, wg, wu, bucket_tok, bucket_gate, count, base, A);
    down_kernel<<<NEXP * 32, 256, 0, stream>>>(A, wd, bucket_tok, count, base, out);
}

// Round 3
// 419.613 us; speedup vs baseline: 3.0640x; 3.0640x over previous
//
#include <hip/hip_runtime.h>
#include <hip/hip_bf16.h>
#include <math.h>

#define HIDDEN 2048
#define INTER 1024
#define NEXP 64
#define TOPK 8
#define NTOK 512

#define MT 96                 // M tile rows (6 x 16)
#define BK 32                 // K step
#define ROWB 80               // LDS row stride bytes: 32 bf16 = 64B + 16B pad
#define WROWS 256             // W^T rows per buffer (cols of W covered per block)
#define WTB (WROWS * ROWB)    // 20480 B
#define XOFF WTB
#define BUFB (WTB + MT * ROWB)  // 28160 B per buffer
#define AWS_ROWS (NTOK * TOPK + 128)

typedef float floatx4 __attribute__((ext_vector_type(4)));
typedef short shortx8 __attribute__((ext_vector_type(8)));

__device__ __forceinline__ unsigned short bfbits(float f) {
    union { __hip_bfloat16 h; unsigned short u; } c;
    c.h = __float2bfloat16(f);
    return c.u;
}
// pack 4 floats (k-ascending) into 2 dwords of bf16, k-ascending in memory
__device__ __forceinline__ uint2 pack4(float4 v) {
    uint2 r;
    r.x = ((unsigned)bfbits(v.y) << 16) | (unsigned)bfbits(v.x);
    r.y = ((unsigned)bfbits(v.w) << 16) | (unsigned)bfbits(v.z);
    return r;
}

// ---------------- Router + top-8 + softmax ----------------
__global__ void router_topk_kernel(const float* __restrict__ x,
                                   const float* __restrict__ wr,
                                   int* __restrict__ topk_idx,
                                   float* __restrict__ gates) {
    const int t = blockIdx.x;
    const int lane = threadIdx.x;
    __shared__ float sx[HIDDEN];
    for (int i = lane; i < HIDDEN / 4; i += 64)
        *(float4*)&sx[i * 4] = *(const float4*)(x + (size_t)t * HIDDEN + i * 4);
    __syncthreads();

    float a0 = 0.f, a1 = 0.f, a2 = 0.f, a3 = 0.f;
#pragma unroll 4
    for (int d = 0; d < HIDDEN; d += 4) {
        a0 = fmaf(sx[d + 0], wr[(d + 0) * NEXP + lane], a0);
        a1 = fmaf(sx[d + 1], wr[(d + 1) * NEXP + lane], a1);
        a2 = fmaf(sx[d + 2], wr[(d + 2) * NEXP + lane], a2);
        a3 = fmaf(sx[d + 3], wr[(d + 3) * NEXP + lane], a3);
    }
    float cur = (a0 + a1) + (a2 + a3);

    float topv[TOPK];
    int topi[TOPK];
#pragma unroll
    for (int k = 0; k < TOPK; ++k) {
        float bv = cur;
        int bi = lane;
#pragma unroll
        for (int off = 32; off > 0; off >>= 1) {
            float ov = __shfl_xor(bv, off, 64);
            int oi = __shfl_xor(bi, off, 64);
            if (ov > bv || (ov == bv && oi < bi)) { bv = ov; bi = oi; }
        }
        topv[k] = bv;
        topi[k] = bi;
        if (lane == bi) cur = -INFINITY;
    }
    if (lane == 0) {
        float m = topv[0];
        float ex[TOPK], s = 0.f;
#pragma unroll
        for (int k = 0; k < TOPK; ++k) { ex[k] = __expf(topv[k] - m); s += ex[k]; }
        float inv = 1.f / s;
#pragma unroll
        for (int k = 0; k < TOPK; ++k) {
            gates[t * TOPK + k] = ex[k] * inv;
            topk_idx[t * TOPK + k] = topi[k];
        }
    }
}

// ---------------- Deterministic bucket build ----------------
__global__ void build_buckets_kernel(const int* __restrict__ topk_idx,
                                     const float* __restrict__ gates,
                                     int* __restrict__ bucket_tok,
                                     float* __restrict__ bucket_gate,
                                     int* __restrict__ count) {
    const int e = blockIdx.x;
    const int tid = threadIdx.x;
    __shared__ int scan[256];
    const int t0 = tid * 2;
    int f0 = 0, f1 = 0;
    float g0 = 0.f, g1 = 0.f;
#pragma unroll
    for (int k = 0; k < TOPK; ++k) {
        if (topk_idx[t0 * TOPK + k] == e) { f0 = 1; g0 = gates[t0 * TOPK + k]; }
        if (topk_idx[(t0 + 1) * TOPK + k] == e) { f1 = 1; g1 = gates[(t0 + 1) * TOPK + k]; }
    }
    int s = f0 + f1;
    scan[tid] = s;
    __syncthreads();
    for (int off = 1; off < 256; off <<= 1) {
        int add = (tid >= off) ? scan[tid - off] : 0;
        __syncthreads();
        scan[tid] += add;
        __syncthreads();
    }
    int excl = scan[tid] - s;
    if (f0) { bucket_tok[e * NTOK + excl] = t0; bucket_gate[e * NTOK + excl] = g0; }
    if (f1) { bucket_tok[e * NTOK + excl + f0] = t0 + 1; bucket_gate[e * NTOK + excl + f0] = g1; }
    if (tid == 255) count[e] = scan[255];
}

__global__ void base_scan_kernel(const int* __restrict__ count, int* __restrict__ base) {
    if (threadIdx.x == 0) {
        int acc = 0;
        for (int e = 0; e < NEXP; ++e) { base[e] = acc; acc += count[e]; }
    }
}

// ---------------- Fused gate/up + SiLU (bf16 MFMA) ----------------
// grid 512: e = bid&63, chunk = bid>>6 covers 128 gate cols + 128 up cols.
// LDS W^T tile: row = col index (0..127 gate, 128..255 up), 32 bf16 k-contiguous.
// Both MFMA operands are contiguous bf16x8 ds_read_b128 (verified m97 recipe).
__global__ __launch_bounds__(256, 2) void gateup_mfma(
    const float* __restrict__ x, const float* __restrict__ wg,
    const float* __restrict__ wu, const int* __restrict__ bucket_tok,
    const float* __restrict__ bucket_gate, const int* __restrict__ count,
    const int* __restrict__ base, __hip_bfloat16* __restrict__ Aws) {
    const int e = blockIdx.x & 63;
    const int c0 = (blockIdx.x >> 6) * 128;
    const int n = count[e];
    if (n == 0) return;
    const int b0 = base[e];

    __shared__ char smem[2 * BUFB + 2 * MT * 4] __attribute__((aligned(16)));
    int* stok = (int*)(smem + 2 * BUFB);
    float* sgate = (float*)(smem + 2 * BUFB + MT * 4);

    const int tid = threadIdx.x;
    const int lane = tid & 63, w = tid >> 6;
    const int q = lane >> 4, r16 = lane & 15;

    const float* wge = wg + (size_t)e * HIDDEN * INTER + c0;
    const float* wue = wu + (size_t)e * HIDDEN * INTER + c0;

    // W staging decode: slot i -> (gate/up, col 0..127, k-quad 0..7)
    int wcol[8], wkq[8];
    unsigned wlds[8];
#pragma unroll
    for (int i = 0; i < 8; ++i) {
        int rem = (i & 3) * 256 + tid;
        wcol[i] = rem & 127;
        wkq[i] = rem >> 7;
        wlds[i] = (unsigned)((((i < 4) ? 0 : 128) + wcol[i]) * ROWB + wkq[i] * 8);
    }

    for (int m0 = 0; m0 < n; m0 += MT) {
        __syncthreads();
        if (tid < MT) {
            int p = m0 + tid;
            stok[tid] = (p < n) ? bucket_tok[e * NTOK + p] : 0;
            sgate[tid] = (p < n) ? bucket_gate[e * NTOK + p] : 0.f;
        }
        __syncthreads();

        const float* wp[8];
#pragma unroll
        for (int i = 0; i < 8; ++i)
            wp[i] = ((i < 4) ? wge : wue) + (size_t)(wkq[i] * 4) * INTER + wcol[i];
        const float* xp[3];
        unsigned xlds[3];
#pragma unroll
        for (int i = 0; i < 3; ++i) {
            int slot = i * 256 + tid;
            int row = slot >> 3, ch = slot & 7;
            xp[i] = x + (size_t)stok[row] * HIDDEN + ch * 4;
            xlds[i] = (unsigned)(XOFF + row * ROWB + ch * 8);
        }

        floatx4 acc[6][4];
#pragma unroll
        for (int ms = 0; ms < 6; ++ms)
#pragma unroll
            for (int s = 0; s < 4; ++s) acc[ms][s] = (floatx4){0.f, 0.f, 0.f, 0.f};

        float wr_[8][4];
        float4 xr_[3];
#pragma unroll
        for (int i = 0; i < 8; ++i) {
#pragma unroll
            for (int j = 0; j < 4; ++j) wr_[i][j] = wp[i][(size_t)j * INTER];
            wp[i] += BK * INTER;
        }
#pragma unroll
        for (int i = 0; i < 3; ++i) { xr_[i] = *(const float4*)xp[i]; xp[i] += BK; }

        for (int kt = 0; kt < HIDDEN / BK; ++kt) {
            char* buf = smem + (kt & 1) * BUFB;
            // ---- write phase (compiler waits vmcnt on wr_/xr_) ----
#pragma unroll
            for (int i = 0; i < 8; ++i) {
                float4 v = {wr_[i][0], wr_[i][1], wr_[i][2], wr_[i][3]};
                *(uint2*)(buf + wlds[i]) = pack4(v);
            }
#pragma unroll
            for (int i = 0; i < 3; ++i)
                *(uint2*)(buf + xlds[i]) = pack4(xr_[i]);
            __syncthreads();
            // ---- issue next K-tile's global loads (fly under MFMA) ----
            if (kt + 1 < HIDDEN / BK) {
#pragma unroll
                for (int i = 0; i < 8; ++i) {
#pragma unroll
                    for (int j = 0; j < 4; ++j) wr_[i][j] = wp[i][(size_t)j * INTER];
                    wp[i] += BK * INTER;
                }
#pragma unroll
                for (int i = 0; i < 3; ++i) { xr_[i] = *(const float4*)xp[i]; xp[i] += BK; }
            }
            // ---- fragments: contiguous bf16x8, same slot->k convention both sides ----
            shortx8 bfr[4];
#pragma unroll
            for (int s = 0; s < 4; ++s) {
                int sub = (s < 2) ? (2 * w + s) : (8 + 2 * w + (s - 2));
                bfr[s] = *(const shortx8*)(buf + (sub * 16 + r16) * ROWB + q * 16);
            }
            shortx8 afr[6];
#pragma unroll
            for (int ms = 0; ms < 6; ++ms)
                afr[ms] = *(const shortx8*)(buf + XOFF + (ms * 16 + r16) * ROWB + q * 16);
#pragma unroll
            for (int ms = 0; ms < 6; ++ms)
#pragma unroll
                for (int s = 0; s < 4; ++s)
                    acc[ms][s] = __builtin_amdgcn_mfma_f32_16x16x32_bf16(afr[ms], bfr[s], acc[ms][s], 0, 0, 0);
            __syncthreads();
        }
        // ---- epilogue: A = silu(h) * u * gate, bf16 ----
        // C layout: col = lane&15, row = 4*(lane>>4) + reg (m89-verified)
#pragma unroll
        for (int ms = 0; ms < 6; ++ms) {
#pragma unroll
            for (int j = 0; j < 2; ++j) {
                floatx4 h4 = acc[ms][j], u4 = acc[ms][j + 2];
#pragma unroll
                for (int rr = 0; rr < 4; ++rr) {
                    int ml = ms * 16 + 4 * q + rr;
                    int p = m0 + ml;
                    if (p < n) {
                        float hv = h4[rr];
                        float av = hv / (1.f + __expf(-hv)) * u4[rr] * sgate[ml];
                        int col = c0 + (2 * w + j) * 16 + r16;
                        Aws[(size_t)(b0 + p) * INTER + col] = __float2bfloat16(av);
                    }
                }
            }
        }
    }
}

// ---------------- Down projection (bf16 MFMA) + scatter-add ----------------
// grid 512: e = bid&63, chunk = bid>>6 covers 256 out cols.
__global__ __launch_bounds__(256, 2) void down_mfma(
    const __hip_bfloat16* __restrict__ Aws, const float* __restrict__ wd,
    const int* __restrict__ bucket_tok, const int* __restrict__ count,
    const int* __restrict__ base, float* __restrict__ out) {
    const int e = blockIdx.x & 63;
    const int c0 = (blockIdx.x >> 6) * 256;
    const int n = count[e];
    if (n == 0) return;
    const int b0 = base[e];

    __shared__ char smem[2 * BUFB + MT * 4] __attribute__((aligned(16)));
    int* stok = (int*)(smem + 2 * BUFB);

    const int tid = threadIdx.x;
    const int lane = tid & 63, w = tid >> 6;
    const int q = lane >> 4, r16 = lane & 15;

    const float* wde = wd + (size_t)e * INTER * HIDDEN + c0;

    int wcol[8], wkq[8];
    unsigned wlds[8];
#pragma unroll
    for (int i = 0; i < 8; ++i) {
        int slot = i * 256 + tid;
        wcol[i] = slot & 255;
        wkq[i] = slot >> 8;      // 0..7
        wlds[i] = (unsigned)(wcol[i] * ROWB + wkq[i] * 8);
    }
    const int slot1 = 256 + tid;
    const bool a1v = tid < 128;

    for (int m0 = 0; m0 < n; m0 += MT) {
        __syncthreads();
        if (tid < MT) {
            int p = m0 + tid;
            stok[tid] = (p < n) ? bucket_tok[e * NTOK + p] : 0;
        }
        __syncthreads();

        const float* wp[8];
#pragma unroll
        for (int i = 0; i < 8; ++i)
            wp[i] = wde + (size_t)(wkq[i] * 4) * HIDDEN + wcol[i];
        const __hip_bfloat16* ap0 = Aws + (size_t)(b0 + m0 + (tid >> 2)) * INTER + (tid & 3) * 8;
        const __hip_bfloat16* ap1 = Aws + (size_t)(b0 + m0 + (slot1 >> 2)) * INTER + (slot1 & 3) * 8;
        const unsigned alds0 = (unsigned)(XOFF + (tid >> 2) * ROWB + (tid & 3) * 16);
        const unsigned alds1 = (unsigned)(XOFF + (slot1 >> 2) * ROWB + (slot1 & 3) * 16);

        floatx4 acc[6][4];
#pragma unroll
        for (int ms = 0; ms < 6; ++ms)
#pragma unroll
            for (int s = 0; s < 4; ++s) acc[ms][s] = (floatx4){0.f, 0.f, 0.f, 0.f};

        float wr_[8][4];
        uint4 ar0, ar1;
#pragma unroll
        for (int i = 0; i < 8; ++i) {
#pragma unroll
            for (int j = 0; j < 4; ++j) wr_[i][j] = wp[i][(size_t)j * HIDDEN];
            wp[i] += BK * HIDDEN;
        }
        ar0 = *(const uint4*)ap0; ap0 += BK;
        if (a1v) { ar1 = *(const uint4*)ap1; ap1 += BK; }

        for (int kt = 0; kt < INTER / BK; ++kt) {
            char* buf = smem + (kt & 1) * BUFB;
#pragma unroll
            for (int i = 0; i < 8; ++i) {
                float4 v = {wr_[i][0], wr_[i][1], wr_[i][2], wr_[i][3]};
                *(uint2*)(buf + wlds[i]) = pack4(v);
            }
            *(uint4*)(buf + alds0) = ar0;
            if (a1v) *(uint4*)(buf + alds1) = ar1;
            __syncthreads();
            if (kt + 1 < INTER / BK) {
#pragma unroll
                for (int i = 0; i < 8; ++i) {
#pragma unroll
                    for (int j = 0; j < 4; ++j) wr_[i][j] = wp[i][(size_t)j * HIDDEN];
                    wp[i] += BK * HIDDEN;
                }
                ar0 = *(const uint4*)ap0; ap0 += BK;
                if (a1v) { ar1 = *(const uint4*)ap1; ap1 += BK; }
            }
            shortx8 bfr[4];
#pragma unroll
            for (int s = 0; s < 4; ++s)
                bfr[s] = *(const shortx8*)(buf + ((4 * w + s) * 16 + r16) * ROWB + q * 16);
            shortx8 afr[6];
#pragma unroll
            for (int ms = 0; ms < 6; ++ms)
                afr[ms] = *(const shortx8*)(buf + XOFF + (ms * 16 + r16) * ROWB + q * 16);
#pragma unroll
            for (int ms = 0; ms < 6; ++ms)
#pragma unroll
                for (int s = 0; s < 4; ++s)
                    acc[ms][s] = __builtin_amdgcn_mfma_f32_16x16x32_bf16(afr[ms], bfr[s], acc[ms][s], 0, 0, 0);
            __syncthreads();
        }
#pragma unroll
        for (int ms = 0; ms < 6; ++ms) {
#pragma unroll
            for (int s = 0; s < 4; ++s) {
#pragma unroll
                for (int rr = 0; rr < 4; ++rr) {
                    int ml = ms * 16 + 4 * q + rr;
                    int p = m0 + ml;
                    if (p < n) {
                        int col = c0 + (4 * w + s) * 16 + r16;
                        unsafeAtomicAdd(&out[(size_t)stok[ml] * HIDDEN + col], acc[ms][s][rr]);
                    }
                }
            }
        }
    }
}

extern "C" void kernel_launch(void* const* d_in, const int* in_sizes, int n_in,
                              void* d_out, int out_size, void* d_ws, size_t ws_size,
                              hipStream_t stream) {
    const float* x = (const float*)d_in[0];
    const float* wr = (const float*)d_in[1];
    const float* wg = (const float*)d_in[2];
    const float* wu = (const float*)d_in[3];
    const float* wd = (const float*)d_in[4];
    float* out = (float*)d_out;

    char* ws = (char*)d_ws;
    size_t off = 0;
    auto alloc = [&](size_t bytes) {
        void* p = ws + off;
        off = (off + bytes + 255) & ~(size_t)255;
        return p;
    };
    int* topk_idx = (int*)alloc(NTOK * TOPK * sizeof(int));
    float* gates = (float*)alloc(NTOK * TOPK * sizeof(float));
    int* bucket_tok = (int*)alloc(NEXP * NTOK * sizeof(int));
    float* bucket_gate = (float*)alloc(NEXP * NTOK * sizeof(float));
    int* count = (int*)alloc(NEXP * sizeof(int));
    int* base = (int*)alloc(NEXP * sizeof(int));
    __hip_bfloat16* Aws = (__hip_bfloat16*)alloc((size_t)AWS_ROWS * INTER * sizeof(__hip_bfloat16));
    (void)ws_size;

    hipMemsetAsync(d_out, 0, (size_t)NTOK * HIDDEN * sizeof(float), stream);

    router_topk_kernel<<<NTOK, 64, 0, stream>>>(x, wr, topk_idx, gates);
    build_buckets_kernel<<<NEXP, 256, 0, stream>>>(topk_idx, gates, bucket_tok, bucket_gate, count);
    base_scan_kernel<<<1, 64, 0, stream>>>(count, base);
    gateup_mfma<<<NEXP * 8, 256, 0, stream>>>(x, wg, wu, bucket_tok, bucket_gate, count, base, Aws);
    down_mfma<<<NEXP * 8, 256, 0, stream>>>(Aws, wd, bucket_tok, count, base, out);
}